// Round 4
// baseline (262.052 us; speedup 1.0000x reference)
//
#include <hip/hip_runtime.h>
#include <hip/hip_bf16.h>
#include <math.h>

// GCN 3-layer forward, MI355X. R15: predicated flat-batch aggregation.
//  agg128: 32 edges/iter (8 slots x 4 q-groups, weight-0 predication) ->
//  whole gather of a deg<=31 node in ONE latency round (8 csr + 8 dinv +
//  8 hn loads in flight). agg40: 16 edges/iter same scheme.
//  D2: bucket || GEMM1 (x prefetched, swapped-operand MFMA, packed stores).
//  D3: per-partition LDS counting sort. 8 dispatches.
// hn stays UNSCALED; dinv applied at gather.

#define F_IN  256
#define F_MID 128
#define F_OUT 40
#define PSH   9        // partition shift: 512 dst nodes per partition
#define BCAP2 10240    // per-partition capacity (avg 8192, +22 sigma)

typedef __attribute__((ext_vector_type(8))) short bf16x8;
typedef __attribute__((ext_vector_type(4))) float f32x4;

union FragU {
    bf16x8 v;
    __hip_bfloat162 h2[4];
    uint4 u;
    unsigned short s[8];
};

__device__ __forceinline__ unsigned int f2bf(float f) {
    unsigned int u = __float_as_uint(f);
    return (u + 0x7fffu + ((u >> 16) & 1u)) >> 16;   // RNE bf16
}
__device__ __forceinline__ float bf_lo(unsigned int u) { return __uint_as_float(u << 16); }
__device__ __forceinline__ float bf_hi(unsigned int u) { return __uint_as_float(u & 0xffff0000u); }

// ---------------- D1: zero bcur | prepW(1,2,3) ----------------
__global__ __launch_bounds__(256) void k_prep0(int* __restrict__ bcur,
                                               const float* __restrict__ W1,
                                               const float* __restrict__ W2,
                                               const float* __restrict__ W3,
                                               unsigned short* __restrict__ Wp1,
                                               unsigned short* __restrict__ Wp2,
                                               unsigned short* __restrict__ Wp3) {
    if (blockIdx.x == 0) {
        if (threadIdx.x < 128) bcur[threadIdx.x] = 0;
        return;
    }
    // ---- W pre-pack: W[K][M] f32 -> Wp[(k/8)*Mp + n][8] bf16 ----
    int t = (blockIdx.x - 1) * 256 + threadIdx.x;
    const float* W; unsigned short* Wp; int M, Mp, kc, nn;
    if (t < 4096)      { W = W1; Wp = Wp1; M = 128; Mp = 128; kc = t >> 7; nn = t & 127; }
    else if (t < 6144) { t -= 4096; W = W2; Wp = Wp2; M = 128; Mp = 128; kc = t >> 7; nn = t & 127; }
    else if (t < 6912) { t -= 6144; W = W3; Wp = Wp3; M = 40;  Mp = 48;  kc = t / 48; nn = t % 48; }
    else return;
    FragU o;
#pragma unroll
    for (int j = 0; j < 8; ++j) {
        int k = kc * 8 + j;
        o.s[j] = (nn < M) ? (unsigned short)f2bf(W[k * M + nn]) : 0;
    }
    *(uint4*)&Wp[((size_t)kc * Mp + nn) * 8] = o.u;
}

// ---------------- D2: bucket(32 edges/thread) || GEMM1 ----------------
__global__ __launch_bounds__(256) void k_bucket_gemm1(const int* __restrict__ src,
                                                      const int* __restrict__ dst,
                                                      unsigned int* __restrict__ bkt,
                                                      int* __restrict__ bcur,
                                                      int E, int nbBkt,
                                                      const float* __restrict__ x,
                                                      const unsigned short* __restrict__ Wp1,
                                                      unsigned short* __restrict__ hn, int n) {
    if (blockIdx.x < (unsigned)nbBkt) {
        // ---- bucket path: 8192 edges per block, one global-atomic round ----
        __shared__ int hist[128], base[128], cur[128];
        const int t = threadIdx.x;
        if (t < 128) { hist[t] = 0; cur[t] = 0; }
        __syncthreads();
        const int e0 = blockIdx.x * 8192;
        unsigned int mye[32];
#pragma unroll
        for (int j = 0; j < 32; ++j) {
            int e = e0 + j * 256 + t;
            if (e < E) {
                mye[j] = ((unsigned int)dst[e] << 16) | (unsigned int)src[e];
                atomicAdd(&hist[mye[j] >> (16 + PSH)], 1);
            } else mye[j] = 0xffffffffu;
        }
        __syncthreads();
        if (t < 128) base[t] = hist[t] ? atomicAdd(&bcur[t], hist[t]) : 0;
        __syncthreads();
#pragma unroll
        for (int j = 0; j < 32; ++j) {
            if (mye[j] != 0xffffffffu) {
                int p = mye[j] >> (16 + PSH);
                int pos = base[p] + atomicAdd(&cur[p], 1);
                if (pos < BCAP2) bkt[(size_t)p * BCAP2 + pos] = mye[j];
            }
        }
        return;
    }
    // ---- GEMM1 path: K=256, M=128, full x-row prefetch, swapped store ----
    const int t = threadIdx.x;
    const int w = t >> 6, lane = t & 63, sub = lane & 15, q = lane >> 4;
    const int row0 = (blockIdx.x - nbBkt) * 64 + w * 16;
    const int row = row0 + sub;
    const bool rv = row < n;
    const float* ap = x + (size_t)row * 256;

    float4 xv[16];
    if (rv) {
#pragma unroll
        for (int j = 0; j < 16; ++j)
            xv[j] = *(const float4*)(ap + (j >> 1) * 32 + q * 8 + (j & 1) * 4);
    } else {
#pragma unroll
        for (int j = 0; j < 16; ++j) xv[j] = make_float4(0.f, 0.f, 0.f, 0.f);
    }

    f32x4 acc[8];
#pragma unroll
    for (int cg = 0; cg < 8; ++cg) acc[cg] = (f32x4)0.f;

#pragma unroll
    for (int kk = 0; kk < 8; ++kk) {
        FragU af;
        float4 f0 = xv[2 * kk];
        float4 f1 = xv[2 * kk + 1];
        af.h2[0] = __float22bfloat162_rn(make_float2(f0.x, f0.y));
        af.h2[1] = __float22bfloat162_rn(make_float2(f0.z, f0.w));
        af.h2[2] = __float22bfloat162_rn(make_float2(f1.x, f1.y));
        af.h2[3] = __float22bfloat162_rn(make_float2(f1.z, f1.w));
        const unsigned short* wrow = Wp1 + (size_t)((kk * 4 + q) * 128 + sub) * 8;
#pragma unroll
        for (int cg = 0; cg < 8; ++cg) {
            bf16x8 b = *(const bf16x8*)(wrow + cg * 16 * 8);
            acc[cg] = __builtin_amdgcn_mfma_f32_16x16x32_bf16(b, af.v, acc[cg], 0, 0, 0);
        }
    }
    // swapped layout: lane(q,sub) holds features cg*16+q*4+{0..3} of node row
    if (rv) {
#pragma unroll
        for (int cg = 0; cg < 8; ++cg) {
            uint2 pk;
            pk.x = f2bf(acc[cg][0]) | (f2bf(acc[cg][1]) << 16);
            pk.y = f2bf(acc[cg][2]) | (f2bf(acc[cg][3]) << 16);
            *(uint2*)(hn + (size_t)row * 128 + cg * 16 + q * 4) = pk;
        }
    }
}

// ---------------- D3: per-partition LDS counting sort (batched) ----------
__global__ __launch_bounds__(256) void k_sort(const unsigned int* __restrict__ bkt,
                                              const int* __restrict__ bcur,
                                              int* __restrict__ rofs,
                                              float* __restrict__ dinv,
                                              unsigned short* __restrict__ csr,
                                              int npart, int n) {
    __shared__ int hist[512];
    __shared__ int stmp[256];
    const int p = blockIdx.x;
    const int t = threadIdx.x;
    const int d0 = p << PSH;
    const int nd = min(512, n - d0);

    int bv = (t < p) ? bcur[t] : 0;
    bv = bv > BCAP2 ? BCAP2 : bv;
    stmp[t] = bv;
    hist[t] = 0; hist[t + 256] = 0;
    __syncthreads();
#pragma unroll
    for (int off = 128; off; off >>= 1) {
        if (t < off) stmp[t] += stmp[t + off];
        __syncthreads();
    }
    const int base = stmp[0];
    int np = bcur[p]; np = np > BCAP2 ? BCAP2 : np;
    const unsigned int* b = bkt + (size_t)p * BCAP2;

    // pass A: histogram, 8-deep batched loads
    for (int i0 = t; i0 < np; i0 += 2048) {
        unsigned int ee[8];
#pragma unroll
        for (int j = 0; j < 8; ++j) {
            int idx = i0 + j * 256;
            ee[j] = (idx < np) ? b[idx] : 0xffffffffu;
        }
#pragma unroll
        for (int j = 0; j < 8; ++j)
            if (ee[j] != 0xffffffffu)
                atomicAdd(&hist[(int)(ee[j] >> 16) - d0], 1);
    }
    __syncthreads();

    // pair-wise inclusive scan of 512 counters via 256 pair-sums
    const int h0 = hist[2 * t], h1 = hist[2 * t + 1];
    __syncthreads();
    stmp[t] = h0 + h1;
    __syncthreads();
#pragma unroll
    for (int off = 1; off < 256; off <<= 1) {
        int xx = (t >= off) ? stmp[t - off] : 0;
        __syncthreads();
        stmp[t] += xx;
        __syncthreads();
    }
    const int excl = stmp[t] - (h0 + h1);   // exclusive prefix of pair 2t

    // cursors + rofs + dinv
    hist[2 * t] = excl;
    hist[2 * t + 1] = excl + h0;
    if (2 * t < nd) {
        rofs[d0 + 2 * t] = base + excl;
        dinv[d0 + 2 * t] = rsqrtf((float)(h0 + 1));
    }
    if (2 * t + 1 < nd) {
        rofs[d0 + 2 * t + 1] = base + excl + h0;
        dinv[d0 + 2 * t + 1] = rsqrtf((float)(h1 + 1));
    }
    if (p == npart - 1 && t == 0) rofs[n] = base + np;
    __syncthreads();

    // pass B: placement, 8-deep batched loads + LDS cursor atomics
    for (int i0 = t; i0 < np; i0 += 2048) {
        unsigned int ee[8];
#pragma unroll
        for (int j = 0; j < 8; ++j) {
            int idx = i0 + j * 256;
            ee[j] = (idx < np) ? b[idx] : 0xffffffffu;
        }
#pragma unroll
        for (int j = 0; j < 8; ++j) {
            if (ee[j] != 0xffffffffu) {
                int ld = (int)(ee[j] >> 16) - d0;
                int pos = atomicAdd(&hist[ld], 1);
                csr[base + pos] = (unsigned short)(ee[j] & 0xffffu);
            }
        }
    }
}

// ---------------- MFMA GEMMs 2/3 (prefetched A, swapped store) ------------
template <int K>
__global__ __launch_bounds__(256) void gemm_mfma_bf16A(const unsigned short* __restrict__ A,
                                                       const unsigned short* __restrict__ Wp,
                                                       unsigned short* __restrict__ hn, int n) {
    const int t = threadIdx.x;
    const int w = t >> 6, lane = t & 63, sub = lane & 15, q = lane >> 4;
    const int row0 = blockIdx.x * 64 + w * 16;
    const int row = row0 + sub;
    const bool rv = row < n;
    const unsigned short* ap = A + (size_t)row * K;

    uint4 xv[K / 32];
    if (rv) {
#pragma unroll
        for (int j = 0; j < K / 32; ++j)
            xv[j] = *(const uint4*)(ap + j * 32 + q * 8);
    } else {
#pragma unroll
        for (int j = 0; j < K / 32; ++j) xv[j] = make_uint4(0, 0, 0, 0);
    }

    f32x4 acc[8];
#pragma unroll
    for (int cg = 0; cg < 8; ++cg) acc[cg] = (f32x4)0.f;

#pragma unroll
    for (int kk = 0; kk < K / 32; ++kk) {
        FragU af; af.u = xv[kk];
        const unsigned short* wrow = Wp + (size_t)((kk * 4 + q) * 128 + sub) * 8;
#pragma unroll
        for (int cg = 0; cg < 8; ++cg) {
            bf16x8 b = *(const bf16x8*)(wrow + cg * 16 * 8);
            acc[cg] = __builtin_amdgcn_mfma_f32_16x16x32_bf16(b, af.v, acc[cg], 0, 0, 0);
        }
    }

    if (rv) {
#pragma unroll
        for (int cg = 0; cg < 8; ++cg) {
            uint2 pk;
            pk.x = f2bf(acc[cg][0]) | (f2bf(acc[cg][1]) << 16);
            pk.y = f2bf(acc[cg][2]) | (f2bf(acc[cg][3]) << 16);
            *(uint2*)(hn + (size_t)row * 128 + cg * 16 + q * 4) = pk;
        }
    }
}

__global__ __launch_bounds__(256) void gemm_mfma_m40(const unsigned short* __restrict__ A,
                                                     const unsigned short* __restrict__ Wp,
                                                     unsigned short* __restrict__ hn, int n) {
    const int K = 128;
    const int t = threadIdx.x;
    const int w = t >> 6, lane = t & 63, sub = lane & 15, q = lane >> 4;
    const int row0 = blockIdx.x * 64 + w * 16;
    const int row = row0 + sub;
    const bool rv = row < n;
    const unsigned short* ap = A + (size_t)row * K;

    uint4 xv[4];
    if (rv) {
#pragma unroll
        for (int j = 0; j < 4; ++j)
            xv[j] = *(const uint4*)(ap + j * 32 + q * 8);
    } else {
#pragma unroll
        for (int j = 0; j < 4; ++j) xv[j] = make_uint4(0, 0, 0, 0);
    }

    f32x4 acc[3];
#pragma unroll
    for (int cg = 0; cg < 3; ++cg) acc[cg] = (f32x4)0.f;

#pragma unroll
    for (int kk = 0; kk < 4; ++kk) {
        FragU af; af.u = xv[kk];
        const unsigned short* wrow = Wp + (size_t)((kk * 4 + q) * 48 + sub) * 8;
#pragma unroll
        for (int cg = 0; cg < 3; ++cg) {
            bf16x8 b = *(const bf16x8*)(wrow + cg * 16 * 8);
            acc[cg] = __builtin_amdgcn_mfma_f32_16x16x32_bf16(b, af.v, acc[cg], 0, 0, 0);
        }
    }

    if (rv) {
#pragma unroll
        for (int cg = 0; cg < 3; ++cg) {
            int feat = cg * 16 + q * 4;
            if (feat < 40) {
                uint2 pk;
                pk.x = f2bf(acc[cg][0]) | (f2bf(acc[cg][1]) << 16);
                pk.y = f2bf(acc[cg][2]) | (f2bf(acc[cg][3]) << 16);
                *(uint2*)(hn + (size_t)row * 40 + feat) = pk;
            }
        }
    }
}

// ---------------- aggregation (scale-at-gather, flat-batched) -------------
__device__ __forceinline__ void acc_row(float* acc, uint4 u, float dv) {
    acc[0] += dv * bf_lo(u.x); acc[1] += dv * bf_hi(u.x);
    acc[2] += dv * bf_lo(u.y); acc[3] += dv * bf_hi(u.y);
    acc[4] += dv * bf_lo(u.z); acc[5] += dv * bf_hi(u.z);
    acc[6] += dv * bf_lo(u.w); acc[7] += dv * bf_hi(u.w);
}

__global__ __launch_bounds__(256) void agg128_bf16(const unsigned short* __restrict__ hn,
                                                   const int* __restrict__ rofs,
                                                   const unsigned short* __restrict__ csr,
                                                   const float* __restrict__ dinv,
                                                   const float* __restrict__ bias,
                                                   unsigned short* __restrict__ obf, int n) {
    int wid = (blockIdx.x * 256 + threadIdx.x) >> 6;
    if (wid >= n) return;
    const int v = wid;
    const int lane = threadIdx.x & 63;
    const int q = lane >> 4;
    const int sub = lane & 15;
    float acc[8];
#pragma unroll
    for (int k = 0; k < 8; ++k) acc[k] = 0.f;
    const int e0 = rofs[v];
    const int total = rofs[v + 1] - e0 + 1;   // + self loop at i==0

    // 32 edges per iteration: 8 predicated slots per q-group, all loads
    // independent -> one latency round for deg<=31 nodes.
    for (int i0 = 0; i0 < total; i0 += 32) {
        int sA[8]; float dA[8];
#pragma unroll
        for (int j = 0; j < 8; ++j) {
            int ix = i0 + q + 4 * j;
            bool ok = ix < total;
            int s = ok ? ((ix == 0) ? v : (int)csr[e0 + ix - 1]) : v;
            sA[j] = s;
            dA[j] = ok ? dinv[s] : 0.f;
        }
#pragma unroll
        for (int j = 0; j < 8; ++j) {
            uint4 u = *(const uint4*)(hn + (size_t)sA[j] * 128 + sub * 8);
            acc_row(acc, u, dA[j]);
        }
    }
#pragma unroll
    for (int k = 0; k < 8; ++k) {
        acc[k] += __shfl_xor(acc[k], 16);
        acc[k] += __shfl_xor(acc[k], 32);
    }
    if (q == 0) {
        float dv = dinv[v];
        float4 b0 = *(const float4*)(bias + sub * 8);
        float4 b1 = *(const float4*)(bias + sub * 8 + 4);
        float o[8];
        o[0] = fmaxf(dv * acc[0] + b0.x, 0.f);
        o[1] = fmaxf(dv * acc[1] + b0.y, 0.f);
        o[2] = fmaxf(dv * acc[2] + b0.z, 0.f);
        o[3] = fmaxf(dv * acc[3] + b0.w, 0.f);
        o[4] = fmaxf(dv * acc[4] + b1.x, 0.f);
        o[5] = fmaxf(dv * acc[5] + b1.y, 0.f);
        o[6] = fmaxf(dv * acc[6] + b1.z, 0.f);
        o[7] = fmaxf(dv * acc[7] + b1.w, 0.f);
        uint4 pk;
        pk.x = f2bf(o[0]) | (f2bf(o[1]) << 16);
        pk.y = f2bf(o[2]) | (f2bf(o[3]) << 16);
        pk.z = f2bf(o[4]) | (f2bf(o[5]) << 16);
        pk.w = f2bf(o[6]) | (f2bf(o[7]) << 16);
        *(uint4*)(obf + (size_t)v * 128 + sub * 8) = pk;
    }
}

// F=40 agg + bias + log_softmax; flat-batched 16 edges/iter.
__global__ __launch_bounds__(256) void agg40_lsm_bf16(const unsigned short* __restrict__ hn,
                                                      const int* __restrict__ rofs,
                                                      const unsigned short* __restrict__ csr,
                                                      const float* __restrict__ dinv,
                                                      const float* __restrict__ bias,
                                                      float* __restrict__ out, int n) {
    int wid = (blockIdx.x * 256 + threadIdx.x) >> 6;
    if (wid >= n) return;
    const int v = wid;
    const int lane = threadIdx.x & 63;
    const int h = lane >> 5;
    const int sl = lane & 31;
    const bool act = sl < 20;
    float a0 = 0.f, a1 = 0.f;
    const int e0 = rofs[v];
    const int total = rofs[v + 1] - e0 + 1;

    for (int i0 = 0; i0 < total; i0 += 16) {
        int sA[8];
        unsigned char okA[8];
#pragma unroll
        for (int j = 0; j < 8; ++j) {
            int ix = i0 + h + 2 * j;
            bool ok = ix < total;
            sA[j] = ok ? ((ix == 0) ? v : (int)csr[e0 + ix - 1]) : v;
            okA[j] = ok ? 1 : 0;
        }
        if (act) {
#pragma unroll
            for (int j = 0; j < 8; ++j) {
                float d = okA[j] ? dinv[sA[j]] : 0.f;
                unsigned int u = *(const unsigned int*)(hn + (size_t)sA[j] * 40 + sl * 2);
                a0 += d * bf_lo(u);
                a1 += d * bf_hi(u);
            }
        }
    }
    a0 += __shfl_xor(a0, 32);
    a1 += __shfl_xor(a1, 32);
    float dv = dinv[v];
    float v0 = act ? (dv * a0 + bias[sl * 2])     : -3.402823466e38f;
    float v1 = act ? (dv * a1 + bias[sl * 2 + 1]) : -3.402823466e38f;
    float m = fmaxf(v0, v1);
#pragma unroll
    for (int off = 16; off; off >>= 1) m = fmaxf(m, __shfl_xor(m, off));
    float p = act ? (__expf(v0 - m) + __expf(v1 - m)) : 0.f;
#pragma unroll
    for (int off = 16; off; off >>= 1) p += __shfl_xor(p, off);
    if (h == 0 && act) {
        float ls = __logf(p);
        *(float2*)(out + (size_t)v * 40 + sl * 2) = make_float2(v0 - m - ls, v1 - m - ls);
    }
}

// ---------------- launch ----------------

extern "C" void kernel_launch(void* const* d_in, const int* in_sizes, int n_in,
                              void* d_out, int out_size, void* d_ws, size_t ws_size,
                              hipStream_t stream) {
    const float* x     = (const float*)d_in[0];
    const int*   ei    = (const int*)d_in[1];
    const float* W_in  = (const float*)d_in[2];
    const float* b_in  = (const float*)d_in[3];
    const float* W_mid = (const float*)d_in[4];
    const float* b_mid = (const float*)d_in[5];
    const float* W_out = (const float*)d_in[6];
    const float* b_out = (const float*)d_in[7];
    float* out = (float*)d_out;

    const int N = in_sizes[0] / F_IN;   // 50000
    const int E = in_sizes[1] / 2;      // 800000
    const int* srcp = ei;
    const int* dstp = ei + E;
    const int npart = (N + (1 << PSH) - 1) >> PSH;   // 98

    char* w = (char*)d_ws;
    unsigned short* hn  = (unsigned short*)w; w += (size_t)N * 128 * 2; // GEMM out (bf16, unscaled)
    unsigned short* obf = (unsigned short*)w; w += (size_t)N * 128 * 2; // agg out (bf16)
    float* dinv = (float*)w; w += (size_t)N * 4;
    int* bcur   = (int*)w;   w += 512;                       // 128 ints
    int* rofs   = (int*)w;   w += (size_t)(N + 1) * 4 + 12;
    unsigned int* bkt = (unsigned int*)w; w += (size_t)npart * BCAP2 * 4;
    unsigned short* csr = (unsigned short*)w; w += (size_t)E * 2 + 128;  // +64-entry pad for predicated overread
    unsigned short* Wp1 = (unsigned short*)((((size_t)w) + 15) & ~(size_t)15); w = (char*)Wp1 + 32 * 128 * 8 * 2;
    unsigned short* Wp2 = (unsigned short*)w; w += 16 * 128 * 8 * 2;
    unsigned short* Wp3 = (unsigned short*)w; w += 16 * 48 * 8 * 2;

    const int nbW = (N * 64 + 255) / 256;   // wave-per-node grids
    const int nbG = (N + 63) / 64;          // 64 rows per block
    const int nbBkt = (E + 8191) / 8192;    // 98 bucket blocks

    // D1: zero bcur + prepW (28 blocks)
    k_prep0<<<28, 256, 0, stream>>>(bcur, W_in, W_mid, W_out, Wp1, Wp2, Wp3);
    // D2: bucket || GEMM1
    k_bucket_gemm1<<<nbBkt + nbG, 256, 0, stream>>>(srcp, dstp, bkt, bcur, E, nbBkt,
                                                    x, Wp1, hn, N);
    // D3: per-partition counting sort -> rofs/dinv/csr
    k_sort<<<npart, 256, 0, stream>>>(bkt, bcur, rofs, dinv, csr, npart, N);

    // layer 1: hn (unscaled) -> obf (relu, bf16)
    agg128_bf16<<<nbW, 256, 0, stream>>>(hn, rofs, csr, dinv, b_in, obf, N);
    // layer 2
    gemm_mfma_bf16A<128><<<nbG, 256, 0, stream>>>(obf, Wp2, hn, N);
    agg128_bf16<<<nbW, 256, 0, stream>>>(hn, rofs, csr, dinv, b_mid, obf, N);
    // layer 3
    gemm_mfma_m40<<<nbG, 256, 0, stream>>>(obf, Wp3, hn, N);
    agg40_lsm_bf16<<<nbW, 256, 0, stream>>>(hn, rofs, csr, dinv, b_out, out, N);
}

// Round 6
// 229.773 us; speedup vs baseline: 1.1405x; 1.1405x over previous
//
#include <hip/hip_runtime.h>
#include <hip/hip_bf16.h>
#include <math.h>

// GCN 3-layer forward, MI355X. R17 (= R16 resubmit; infra failure last round).
//  D1: bucket(98) || prepW.  D2: GEMM1(x prefetch, unscaled) || sort.
//  D3: hn1 *= dinv[row]; zero-rows for hn1/hn2/hn3 at index N.
//  D4: fused agg1+gemm2 (16 nodes/block: gather->relu->LDS->MFMA->hn2S).
//  D5: fused agg2+gemm3 -> hn3S.  D6: agg40+logsoftmax.
//  Gathers read PRE-SCALED rows (no dinv round); invalid slots hit zero-row N.
// 7 dispatches + 1 memset.

#define F_IN  256
#define F_MID 128
#define F_OUT 40
#define PSH   9        // partition shift: 512 dst nodes per partition
#define BCAP2 10240    // per-partition capacity (avg 8192)

typedef __attribute__((ext_vector_type(8))) short bf16x8;
typedef __attribute__((ext_vector_type(4))) float f32x4;

union FragU {
    bf16x8 v;
    __hip_bfloat162 h2[4];
    uint4 u;
    unsigned short s[8];
};

__device__ __forceinline__ unsigned int f2bf(float f) {
    unsigned int u = __float_as_uint(f);
    return (u + 0x7fffu + ((u >> 16) & 1u)) >> 16;   // RNE bf16
}
__device__ __forceinline__ float bf_lo(unsigned int u) { return __uint_as_float(u << 16); }
__device__ __forceinline__ float bf_hi(unsigned int u) { return __uint_as_float(u & 0xffff0000u); }

__device__ __forceinline__ void add_row(float* acc, uint4 u) {
    acc[0] += bf_lo(u.x); acc[1] += bf_hi(u.x);
    acc[2] += bf_lo(u.y); acc[3] += bf_hi(u.y);
    acc[4] += bf_lo(u.z); acc[5] += bf_hi(u.z);
    acc[6] += bf_lo(u.w); acc[7] += bf_hi(u.w);
}

// ---------------- D1: bucket(98) | prepW(1,2,3) ----------------
__global__ __launch_bounds__(256) void k_bucket_prep(const int* __restrict__ src,
                                                     const int* __restrict__ dst,
                                                     unsigned int* __restrict__ bkt,
                                                     int* __restrict__ bcur,
                                                     int E, int nbBkt,
                                                     const float* __restrict__ W1,
                                                     const float* __restrict__ W2,
                                                     const float* __restrict__ W3,
                                                     unsigned short* __restrict__ Wp1,
                                                     unsigned short* __restrict__ Wp2,
                                                     unsigned short* __restrict__ Wp3) {
    if (blockIdx.x >= (unsigned)nbBkt) {
        int t = (blockIdx.x - nbBkt) * 256 + threadIdx.x;
        const float* W; unsigned short* Wp; int M, Mp, kc, nn;
        if (t < 4096)      { W = W1; Wp = Wp1; M = 128; Mp = 128; kc = t >> 7; nn = t & 127; }
        else if (t < 6144) { t -= 4096; W = W2; Wp = Wp2; M = 128; Mp = 128; kc = t >> 7; nn = t & 127; }
        else if (t < 6912) { t -= 6144; W = W3; Wp = Wp3; M = 40;  Mp = 48;  kc = t / 48; nn = t % 48; }
        else return;
        FragU o;
#pragma unroll
        for (int j = 0; j < 8; ++j) {
            int k = kc * 8 + j;
            o.s[j] = (nn < M) ? (unsigned short)f2bf(W[k * M + nn]) : 0;
        }
        *(uint4*)&Wp[((size_t)kc * Mp + nn) * 8] = o.u;
        return;
    }
    // ---- bucket path: 8192 edges per block, one global-atomic round ----
    __shared__ int hist[128], base[128], cur[128];
    const int t = threadIdx.x;
    if (t < 128) { hist[t] = 0; cur[t] = 0; }
    __syncthreads();
    const int e0 = blockIdx.x * 8192;
    unsigned int mye[32];
#pragma unroll
    for (int j = 0; j < 32; ++j) {
        int e = e0 + j * 256 + t;
        if (e < E) {
            mye[j] = ((unsigned int)dst[e] << 16) | (unsigned int)src[e];
            atomicAdd(&hist[mye[j] >> (16 + PSH)], 1);
        } else mye[j] = 0xffffffffu;
    }
    __syncthreads();
    if (t < 128) base[t] = hist[t] ? atomicAdd(&bcur[t], hist[t]) : 0;
    __syncthreads();
#pragma unroll
    for (int j = 0; j < 32; ++j) {
        if (mye[j] != 0xffffffffu) {
            int p = mye[j] >> (16 + PSH);
            int pos = base[p] + atomicAdd(&cur[p], 1);
            if (pos < BCAP2) bkt[(size_t)p * BCAP2 + pos] = mye[j];
        }
    }
}

// ---------------- D2: GEMM1 (prefetched, unscaled) || sort ----------------
__global__ __launch_bounds__(256) void k_gemm1_sort(const unsigned int* __restrict__ bkt,
                                                    const int* __restrict__ bcur,
                                                    int* __restrict__ rofs,
                                                    float* __restrict__ dinv,
                                                    unsigned short* __restrict__ csr,
                                                    int nbG, int npart,
                                                    const float* __restrict__ x,
                                                    const unsigned short* __restrict__ Wp1,
                                                    unsigned short* __restrict__ hn, int n) {
    __shared__ int sh[768];   // sort: hist[512] + stmp[256]
    if (blockIdx.x >= (unsigned)nbG) {
        int* hist = sh;
        int* stmp = sh + 512;
        const int p = blockIdx.x - nbG;
        const int t = threadIdx.x;
        const int d0 = p << PSH;
        const int nd = min(512, n - d0);

        int bv = (t < p) ? bcur[t] : 0;
        bv = bv > BCAP2 ? BCAP2 : bv;
        stmp[t] = bv;
        hist[t] = 0; hist[t + 256] = 0;
        __syncthreads();
#pragma unroll
        for (int off = 128; off; off >>= 1) {
            if (t < off) stmp[t] += stmp[t + off];
            __syncthreads();
        }
        const int base = stmp[0];
        int np = bcur[p]; np = np > BCAP2 ? BCAP2 : np;
        const unsigned int* b = bkt + (size_t)p * BCAP2;

        for (int i0 = t; i0 < np; i0 += 2048) {
            unsigned int ee[8];
#pragma unroll
            for (int j = 0; j < 8; ++j) {
                int idx = i0 + j * 256;
                ee[j] = (idx < np) ? b[idx] : 0xffffffffu;
            }
#pragma unroll
            for (int j = 0; j < 8; ++j)
                if (ee[j] != 0xffffffffu)
                    atomicAdd(&hist[(int)(ee[j] >> 16) - d0], 1);
        }
        __syncthreads();

        const int h0 = hist[2 * t], h1 = hist[2 * t + 1];
        __syncthreads();
        stmp[t] = h0 + h1;
        __syncthreads();
#pragma unroll
        for (int off = 1; off < 256; off <<= 1) {
            int xx = (t >= off) ? stmp[t - off] : 0;
            __syncthreads();
            stmp[t] += xx;
            __syncthreads();
        }
        const int excl = stmp[t] - (h0 + h1);

        hist[2 * t] = excl;
        hist[2 * t + 1] = excl + h0;
        if (2 * t < nd) {
            rofs[d0 + 2 * t] = base + excl;
            dinv[d0 + 2 * t] = rsqrtf((float)(h0 + 1));
        }
        if (2 * t + 1 < nd) {
            rofs[d0 + 2 * t + 1] = base + excl + h0;
            dinv[d0 + 2 * t + 1] = rsqrtf((float)(h1 + 1));
        }
        if (p == npart - 1 && t == 0) rofs[n] = base + np;
        __syncthreads();

        for (int i0 = t; i0 < np; i0 += 2048) {
            unsigned int ee[8];
#pragma unroll
            for (int j = 0; j < 8; ++j) {
                int idx = i0 + j * 256;
                ee[j] = (idx < np) ? b[idx] : 0xffffffffu;
            }
#pragma unroll
            for (int j = 0; j < 8; ++j) {
                if (ee[j] != 0xffffffffu) {
                    int ld = (int)(ee[j] >> 16) - d0;
                    int pos = atomicAdd(&hist[ld], 1);
                    csr[base + pos] = (unsigned short)(ee[j] & 0xffffu);
                }
            }
        }
        return;
    }
    // ---- GEMM1 path: K=256, M=128, full x-row prefetch, swapped store ----
    const int t = threadIdx.x;
    const int w = t >> 6, lane = t & 63, sub = lane & 15, q = lane >> 4;
    const int row0 = blockIdx.x * 64 + w * 16;
    const int row = row0 + sub;
    const bool rv = row < n;
    const float* ap = x + (size_t)row * 256;

    float4 xv[16];
    if (rv) {
#pragma unroll
        for (int j = 0; j < 16; ++j)
            xv[j] = *(const float4*)(ap + (j >> 1) * 32 + q * 8 + (j & 1) * 4);
    } else {
#pragma unroll
        for (int j = 0; j < 16; ++j) xv[j] = make_float4(0.f, 0.f, 0.f, 0.f);
    }

    f32x4 acc[8];
#pragma unroll
    for (int cg = 0; cg < 8; ++cg) acc[cg] = (f32x4)0.f;

#pragma unroll
    for (int kk = 0; kk < 8; ++kk) {
        FragU af;
        float4 f0 = xv[2 * kk];
        float4 f1 = xv[2 * kk + 1];
        af.h2[0] = __float22bfloat162_rn(make_float2(f0.x, f0.y));
        af.h2[1] = __float22bfloat162_rn(make_float2(f0.z, f0.w));
        af.h2[2] = __float22bfloat162_rn(make_float2(f1.x, f1.y));
        af.h2[3] = __float22bfloat162_rn(make_float2(f1.z, f1.w));
        const unsigned short* wrow = Wp1 + (size_t)((kk * 4 + q) * 128 + sub) * 8;
#pragma unroll
        for (int cg = 0; cg < 8; ++cg) {
            bf16x8 b = *(const bf16x8*)(wrow + cg * 16 * 8);
            acc[cg] = __builtin_amdgcn_mfma_f32_16x16x32_bf16(b, af.v, acc[cg], 0, 0, 0);
        }
    }
    if (rv) {
#pragma unroll
        for (int cg = 0; cg < 8; ++cg) {
            uint2 pk;
            pk.x = f2bf(acc[cg][0]) | (f2bf(acc[cg][1]) << 16);
            pk.y = f2bf(acc[cg][2]) | (f2bf(acc[cg][3]) << 16);
            *(uint2*)(hn + (size_t)row * 128 + cg * 16 + q * 4) = pk;
        }
    }
}

// ---------------- D3: hn1 *= dinv[row]; zero rows N ----------------
__global__ __launch_bounds__(256) void k_scale(unsigned short* __restrict__ hn1,
                                               const float* __restrict__ dinv,
                                               unsigned short* __restrict__ hn2,
                                               unsigned short* __restrict__ hn3,
                                               int n) {
    const int nt = n * 16;   // uint4 units
    for (int i = blockIdx.x * 256 + threadIdx.x; i < nt; i += gridDim.x * 256) {
        int row = i >> 4;
        float dv = dinv[row];
        uint4 u = *(const uint4*)(hn1 + (size_t)i * 8);
        uint4 o;
        o.x = f2bf(dv * bf_lo(u.x)) | (f2bf(dv * bf_hi(u.x)) << 16);
        o.y = f2bf(dv * bf_lo(u.y)) | (f2bf(dv * bf_hi(u.y)) << 16);
        o.z = f2bf(dv * bf_lo(u.z)) | (f2bf(dv * bf_hi(u.z)) << 16);
        o.w = f2bf(dv * bf_lo(u.w)) | (f2bf(dv * bf_hi(u.w)) << 16);
        *(uint4*)(hn1 + (size_t)i * 8) = o;
    }
    if (blockIdx.x == 0) {
        int t = threadIdx.x;
        uint4 z = make_uint4(0, 0, 0, 0);
        if (t < 16) *(uint4*)(hn1 + (size_t)n * 128 + t * 8) = z;
        else if (t < 32) *(uint4*)(hn2 + (size_t)n * 128 + (t - 16) * 8) = z;
        else if (t < 52) ((unsigned int*)(hn3 + (size_t)n * 40))[t - 32] = 0;
    }
}

// ---------------- D4/D5: fused agg + GEMM (16 nodes/block) ----------------
// Agg: 16-lane group per node, lane owns 8 feats; edges via shfl'd csr ids;
// invalid slots read zero-row N. Then ReLU->LDS tile->MFMA vs Wp -> hout
// scaled by dinv[row] (pre-scaled for the NEXT gather).
template <int MOUT, int MP>
__global__ __launch_bounds__(256) void k_agg_gemm(const unsigned short* __restrict__ hnS,
                                                  const int* __restrict__ rofs,
                                                  const unsigned short* __restrict__ csr,
                                                  const float* __restrict__ dinv,
                                                  const float* __restrict__ bias,
                                                  const unsigned short* __restrict__ Wp,
                                                  unsigned short* __restrict__ hout,
                                                  int n) {
    __shared__ unsigned short arows[16][136];   // 272B pitch
    const int t = threadIdx.x;
    const int w = t >> 6, lane = t & 63, sub = lane & 15, q = lane >> 4;
    const int v0 = blockIdx.x * 16;
    const int r = w * 4 + q;
    const int node = v0 + r;
    const bool nv = node < n;

    float acc[8];
#pragma unroll
    for (int k = 0; k < 8; ++k) acc[k] = 0.f;

    int e0 = 0, deg = 0;
    if (nv) { e0 = rofs[node]; deg = rofs[node + 1] - e0; }
    const int total = nv ? deg + 1 : 0;
    int ea = (sub < deg) ? (int)csr[e0 + sub] : n;
    int eb = (16 + sub < deg) ? (int)csr[e0 + 16 + sub] : n;
    const int lim = (total < 33) ? total : 33;

    for (int ix0 = 0; ix0 < lim; ix0 += 8) {
        int sA[8];
#pragma unroll
        for (int jj = 0; jj < 8; ++jj) {
            int ix = ix0 + jj;
            int em = (ix - 1) & 15;
            int srcA = __shfl(ea, (lane & 48) + em);
            int srcB = __shfl(eb, (lane & 48) + em);
            int s = (ix - 1 < 16) ? srcA : srcB;
            s = (ix == 0) ? node : s;
            sA[jj] = (ix < lim) ? s : n;
        }
        uint4 u[8];
#pragma unroll
        for (int jj = 0; jj < 8; ++jj)
            u[jj] = *(const uint4*)(hnS + (size_t)sA[jj] * 128 + sub * 8);
#pragma unroll
        for (int jj = 0; jj < 8; ++jj) add_row(acc, u[jj]);
    }
    // rare tail: deg > 32
    for (int ix = 33; ix < total; ++ix) {
        int s = (int)csr[e0 + ix - 1];
        uint4 u = *(const uint4*)(hnS + (size_t)s * 128 + sub * 8);
        add_row(acc, u);
    }

    // finish: out = dinv[node]*acc + bias, relu -> LDS row r
    uint4 pk = make_uint4(0, 0, 0, 0);
    if (nv) {
        float dv = dinv[node];
        float4 b0 = *(const float4*)(bias + sub * 8);
        float4 b1 = *(const float4*)(bias + sub * 8 + 4);
        float o0 = fmaxf(dv * acc[0] + b0.x, 0.f);
        float o1 = fmaxf(dv * acc[1] + b0.y, 0.f);
        float o2 = fmaxf(dv * acc[2] + b0.z, 0.f);
        float o3 = fmaxf(dv * acc[3] + b0.w, 0.f);
        float o4 = fmaxf(dv * acc[4] + b1.x, 0.f);
        float o5 = fmaxf(dv * acc[5] + b1.y, 0.f);
        float o6 = fmaxf(dv * acc[6] + b1.z, 0.f);
        float o7 = fmaxf(dv * acc[7] + b1.w, 0.f);
        pk.x = f2bf(o0) | (f2bf(o1) << 16);
        pk.y = f2bf(o2) | (f2bf(o3) << 16);
        pk.z = f2bf(o4) | (f2bf(o5) << 16);
        pk.w = f2bf(o6) | (f2bf(o7) << 16);
    }
    *(uint4*)&arows[r][sub * 8] = pk;
    __syncthreads();

    // ---- GEMM phase: 16 rows x K=128 @ Wp -> 16 x MOUT ----
    const int NCG = MP / 16;                 // 8 or 3
    const int NCGW = (MP == 128) ? 2 : 1;    // col-groups per wave
    f32x4 gacc[2];
#pragma unroll
    for (int i = 0; i < 2; ++i) gacc[i] = (f32x4)0.f;

#pragma unroll
    for (int kstep = 0; kstep < 4; ++kstep) {
        FragU af;
        af.u = *(const uint4*)&arows[sub][kstep * 32 + q * 8];
#pragma unroll
        for (int i = 0; i < NCGW; ++i) {
            int cg = w * NCGW + i;
            if (cg < NCG) {
                bf16x8 b = *(const bf16x8*)(Wp + (size_t)((kstep * 4 + q) * MP + cg * 16 + sub) * 8);
                gacc[i] = __builtin_amdgcn_mfma_f32_16x16x32_bf16(b, af.v, gacc[i], 0, 0, 0);
            }
        }
    }
    const int orow = v0 + sub;
    if (orow < n) {
        float dvr = dinv[orow];
#pragma unroll
        for (int i = 0; i < NCGW; ++i) {
            int cg = w * NCGW + i;
            int feat = cg * 16 + q * 4;
            if (cg < NCG && feat < MOUT) {
                uint2 p2;
                p2.x = f2bf(dvr * gacc[i][0]) | (f2bf(dvr * gacc[i][1]) << 16);
                p2.y = f2bf(dvr * gacc[i][2]) | (f2bf(dvr * gacc[i][3]) << 16);
                *(uint2*)(hout + (size_t)orow * MOUT + feat) = p2;
            }
        }
    }
}

// ---------------- D6: agg40 (pre-scaled) + bias + log_softmax ------------
__global__ __launch_bounds__(256) void agg40_lsm_bf16(const unsigned short* __restrict__ hnS,
                                                      const int* __restrict__ rofs,
                                                      const unsigned short* __restrict__ csr,
                                                      const float* __restrict__ dinv,
                                                      const float* __restrict__ bias,
                                                      float* __restrict__ out, int n) {
    int wid = (blockIdx.x * 256 + threadIdx.x) >> 6;
    if (wid >= n) return;
    const int v = wid;
    const int lane = threadIdx.x & 63;
    const int h = lane >> 5;
    const int sl = lane & 31;
    const bool act = sl < 20;
    float a0 = 0.f, a1 = 0.f;
    const int e0 = rofs[v];
    const int total = rofs[v + 1] - e0 + 1;

    for (int i0 = 0; i0 < total; i0 += 16) {
        int sA[8];
#pragma unroll
        for (int j = 0; j < 8; ++j) {
            int ix = i0 + h + 2 * j;
            int s = (ix < total) ? ((ix == 0) ? v : (int)csr[e0 + ix - 1]) : n;
            sA[j] = s;
        }
        if (act) {
#pragma unroll
            for (int j = 0; j < 8; ++j) {
                unsigned int u = *(const unsigned int*)(hnS + (size_t)sA[j] * 40 + sl * 2);
                a0 += bf_lo(u);
                a1 += bf_hi(u);
            }
        }
    }
    a0 += __shfl_xor(a0, 32);
    a1 += __shfl_xor(a1, 32);
    float dv = dinv[v];
    float v0 = act ? (dv * a0 + bias[sl * 2])     : -3.402823466e38f;
    float v1 = act ? (dv * a1 + bias[sl * 2 + 1]) : -3.402823466e38f;
    float m = fmaxf(v0, v1);
#pragma unroll
    for (int off = 16; off; off >>= 1) m = fmaxf(m, __shfl_xor(m, off));
    float p = act ? (__expf(v0 - m) + __expf(v1 - m)) : 0.f;
#pragma unroll
    for (int off = 16; off; off >>= 1) p += __shfl_xor(p, off);
    if (h == 0 && act) {
        float ls = __logf(p);
        *(float2*)(out + (size_t)v * 40 + sl * 2) = make_float2(v0 - m - ls, v1 - m - ls);
    }
}

// ---------------- launch ----------------

extern "C" void kernel_launch(void* const* d_in, const int* in_sizes, int n_in,
                              void* d_out, int out_size, void* d_ws, size_t ws_size,
                              hipStream_t stream) {
    const float* x     = (const float*)d_in[0];
    const int*   ei    = (const int*)d_in[1];
    const float* W_in  = (const float*)d_in[2];
    const float* b_in  = (const float*)d_in[3];
    const float* W_mid = (const float*)d_in[4];
    const float* b_mid = (const float*)d_in[5];
    const float* W_out = (const float*)d_in[6];
    const float* b_out = (const float*)d_in[7];
    float* out = (float*)d_out;

    const int N = in_sizes[0] / F_IN;   // 50000
    const int E = in_sizes[1] / 2;      // 800000
    const int* srcp = ei;
    const int* dstp = ei + E;
    const int npart = (N + (1 << PSH) - 1) >> PSH;   // 98

    char* w = (char*)d_ws;
    unsigned short* hn1 = (unsigned short*)w; w += (size_t)(N + 1) * 128 * 2;
    unsigned short* hn2 = (unsigned short*)w; w += (size_t)(N + 1) * 128 * 2;
    unsigned short* hn3 = (unsigned short*)w; w += (size_t)(N + 1) * 40 * 2 + 16;
    float* dinv = (float*)w; w += (size_t)N * 4;
    int* bcur   = (int*)w;   w += 512;
    int* rofs   = (int*)w;   w += (size_t)(N + 1) * 4 + 12;
    unsigned int* bkt = (unsigned int*)w; w += (size_t)npart * BCAP2 * 4;
    unsigned short* csr = (unsigned short*)w; w += (size_t)E * 2 + 128;
    unsigned short* Wp1 = (unsigned short*)((((size_t)w) + 15) & ~(size_t)15); w = (char*)Wp1 + 32 * 128 * 8 * 2;
    unsigned short* Wp2 = (unsigned short*)w; w += 16 * 128 * 8 * 2;
    unsigned short* Wp3 = (unsigned short*)w; w += 16 * 48 * 8 * 2;

    const int nbW = (N * 64 + 255) / 256;   // wave-per-node grid (agg40)
    const int nbG = (N + 63) / 64;          // gemm1: 64 rows/block
    const int nbF = (N + 15) / 16;          // fused agg+gemm: 16 nodes/block
    const int nbBkt = (E + 8191) / 8192;    // 98

    hipMemsetAsync(bcur, 0, 512, stream);
    // D1: bucket || prepW
    k_bucket_prep<<<nbBkt + 27, 256, 0, stream>>>(srcp, dstp, bkt, bcur, E, nbBkt,
                                                  W_in, W_mid, W_out, Wp1, Wp2, Wp3);
    // D2: GEMM1 (unscaled) || sort -> rofs/dinv/csr
    k_gemm1_sort<<<nbG + npart, 256, 0, stream>>>(bkt, bcur, rofs, dinv, csr,
                                                  nbG, npart, x, Wp1, hn1, N);
    // D3: hn1 *= dinv[row]; zero rows N of hn1/hn2/hn3
    k_scale<<<2048, 256, 0, stream>>>(hn1, dinv, hn2, hn3, N);
    // D4: fused agg1 + gemm2 -> hn2S
    k_agg_gemm<128, 128><<<nbF, 256, 0, stream>>>(hn1, rofs, csr, dinv, b_in, Wp2, hn2, N);
    // D5: fused agg2 + gemm3 -> hn3S
    k_agg_gemm<40, 48><<<nbF, 256, 0, stream>>>(hn2, rofs, csr, dinv, b_mid, Wp3, hn3, N);
    // D6: agg40 + logsoftmax
    agg40_lsm_bf16<<<nbW, 256, 0, stream>>>(hn3, rofs, csr, dinv, b_out, out, N);
}